// Round 1
// 4655.360 us; speedup vs baseline: 1.2993x; 1.2993x over previous
//
#include <hip/hip_runtime.h>

// ---------------------------------------------------------------------------
// LSTM layer, T=512 B=64 I=H=1024, bf16 MFMA path.
// d_in: x[T,B,I], h0[B,H], c0[B,H], W_ih[4H,I], W_hh[4H,H], b_ih[4H], b_hh[4H]
// d_out: outputs[T,B,H] ++ hT[B,H] ++ cT[B,H]  (fp32)
//
// Round 4:
//  - k_xproj rewritten as the verified 128x128-tile / BK=64 double-buffered
//    LDS GEMM (m97 structure): global_load_lds width-16 staging with the
//    XOR bank-swizzle applied on the GLOBAL source address (linear LDS dest),
//    swizzled ds_read_b128 fragment reads, 4 waves x (4x4) 16x16x32 MFMA
//    accumulators. Old version streamed A per-lane from global with W in
//    128 VGPRs (no LDS, 4x A redundancy, spill pressure) -- ~140 TF.
//  - k_lstm byte-identical to round 3 (latency-bound exchange attacked next).
// ---------------------------------------------------------------------------

typedef __attribute__((ext_vector_type(8))) short bf16x8;
typedef __attribute__((ext_vector_type(4))) short bf16x4;
typedef __attribute__((ext_vector_type(4))) float f32x4;
typedef unsigned long long u64;

#define T_STEPS 512
#define BATCH   64
#define HID     1024
#define G4      4096
#define BH      (BATCH * HID)

// ws layout (bytes)
#define OFF_XPT   ((size_t)0)            // bf16 [4096][32768] transposed x-proj (+bias)
#define OFF_RING  ((size_t)268435456)    // bf16 [512][64][1024] h ring (slot t = input of step t)
#define OFF_WIB   ((size_t)335544320)    // bf16 [4096][1024] W_ih
#define OFF_WHB   ((size_t)343932928)    // bf16 [4096][1024] W_hh
#define OFF_BSUM  ((size_t)352321536)    // f32 [4096] b_ih+b_hh
#define OFF_FLG   ((size_t)352337920)    // u32 [4][512][64] per-(row,step,wg) flags

__device__ __forceinline__ unsigned short f2bf(float f) {
  unsigned int u = __float_as_uint(f);
  u += 0x7FFFu + ((u >> 16) & 1u);
  return (unsigned short)(u >> 16);
}
__device__ __forceinline__ float bf2f(short s) {
  return __uint_as_float(((unsigned int)(unsigned short)s) << 16);
}
__device__ __forceinline__ float sigm(float x) { return 1.0f / (1.0f + __expf(-x)); }
__device__ __forceinline__ float tanh_f(float x) {
  float e = __expf(-2.0f * fabsf(x));
  float r = (1.0f - e) / (1.0f + e);
  return x < 0.0f ? -r : r;
}

// async global->LDS, 16B per lane. LDS dest is wave-uniform base + lane*16.
__device__ __forceinline__ void gl_lds16(const unsigned short* g, unsigned short* l) {
  __builtin_amdgcn_global_load_lds(
      (const __attribute__((address_space(1))) unsigned int*)g,
      (__attribute__((address_space(3))) unsigned int*)l, 16, 0, 0);
}

// ---------------------------------------------------------------------------
__global__ void k_cast_bf16(const float* __restrict__ src,
                            unsigned short* __restrict__ dst, int n) {
  int i = (blockIdx.x * 256 + threadIdx.x) * 4;
  if (i >= n) return;
  float4 v = *(const float4*)(src + i);
  bf16x4 o;
  o[0] = (short)f2bf(v.x); o[1] = (short)f2bf(v.y);
  o[2] = (short)f2bf(v.z); o[3] = (short)f2bf(v.w);
  *(bf16x4*)(dst + i) = o;
}

__global__ void k_bias(const float* __restrict__ bi, const float* __restrict__ bh,
                       float* __restrict__ bs) {
  int i = blockIdx.x * 256 + threadIdx.x;
  if (i < G4) bs[i] = bi[i] + bh[i];
}

// ---------------------------------------------------------------------------
// x-projection GEMM: xpT[n][m] = sum_k xb[m][k]*wib[n][k] + bsum[n]  (bf16 out)
// M=32768 (m = t*64+b), N=4096 (gate rows), K=1024. Both operands K-major (NT).
// Tile 128n x 128m, BK=64, 4 waves (each a 64x64 quadrant, 4x4 frags).
// grid 8192 = 256 m-tiles x 32 n-tiles (nt fastest -> m-panel L2 reuse).
__launch_bounds__(256, 2)
__global__ void k_xproj(const unsigned short* __restrict__ xb,
                        const unsigned short* __restrict__ wib,
                        const float* __restrict__ bs,
                        unsigned short* __restrict__ xpT) {
  // [buf][row*64 + unit*8]; LDS holds G[row][unit ^ (row&7)] (source-side swizzle)
  __shared__ __align__(16) unsigned short ldsW[2][128 * 64];
  __shared__ __align__(16) unsigned short ldsX[2][128 * 64];

  const int tid  = threadIdx.x;
  const int lane = tid & 63;
  const int w    = tid >> 6;            // wave 0..3
  const int nt   = blockIdx.x & 31;
  const int mt   = blockIdx.x >> 5;
  const int n0   = nt * 128;
  const int m0   = mt * 128;
  const int col  = lane & 15;
  const int kq   = lane >> 4;           // 0..3 (k-chunk / m-store group)

  // staging: per wave, per q: rows q*32 + w*8 .. +7; lane -> (row=lane>>3, unit=lane&7)
  const int srow = lane >> 3;
  const int swzu = (lane & 7) ^ srow;   // global unit = unit ^ (row&7)

  const unsigned short* wsrc = wib + (size_t)n0 * 1024;
  const unsigned short* xsrc = xb  + (size_t)m0 * 1024;

  const int wm = (w & 1) * 64;          // quadrant within tile
  const int wn = (w >> 1) * 64;

  f32x4 acc[4][4];
#pragma unroll
  for (int i = 0; i < 4; ++i)
#pragma unroll
    for (int j = 0; j < 4; ++j) acc[i][j] = (f32x4){0.f, 0.f, 0.f, 0.f};

  auto STAGE = [&](int b, int kt) {
#pragma unroll
    for (int q = 0; q < 4; ++q) {
      const int rbase = q * 32 + w * 8;                       // wave-uniform
      const size_t goff = (size_t)(rbase + srow) * 1024 + kt * 64 + swzu * 8;
      gl_lds16(wsrc + goff, &ldsW[b][rbase * 64]);
      gl_lds16(xsrc + goff, &ldsX[b][rbase * 64]);
    }
  };

  STAGE(0, 0);
  int buf = 0;
  for (int kt = 0; kt < 16; ++kt) {
    asm volatile("s_waitcnt vmcnt(0)" ::: "memory");
    __syncthreads();                       // staged chunk visible to all waves
    if (kt < 15) STAGE(buf ^ 1, kt + 1);   // prefetch next chunk (other buffer)
#pragma unroll
    for (int ks = 0; ks < 2; ++ks) {
      bf16x8 af[4], bfr[4];
#pragma unroll
      for (int mm = 0; mm < 4; ++mm) {
        const int row = wm + mm * 16 + col;
        const int un  = (ks * 4 + kq) ^ (row & 7);
        af[mm] = *(const bf16x8*)&ldsX[buf][row * 64 + un * 8];
      }
#pragma unroll
      for (int nn = 0; nn < 4; ++nn) {
        const int row = wn + nn * 16 + col;
        const int un  = (ks * 4 + kq) ^ (row & 7);
        bfr[nn] = *(const bf16x8*)&ldsW[buf][row * 64 + un * 8];
      }
#pragma unroll
      for (int mm = 0; mm < 4; ++mm)
#pragma unroll
        for (int nn = 0; nn < 4; ++nn)
          acc[mm][nn] = __builtin_amdgcn_mfma_f32_16x16x32_bf16(
              af[mm], bfr[nn], acc[mm][nn], 0, 0, 0);
    }
    __syncthreads();                       // all reads of buf done before restage
    buf ^= 1;
  }

  // epilogue: bias + bf16 store (D layout: col=lane&15 -> n, (lane>>4)*4+r -> m)
#pragma unroll
  for (int nn = 0; nn < 4; ++nn) {
    const int nrow = n0 + wn + nn * 16 + col;
    const float bias = bs[nrow];
#pragma unroll
    for (int mm = 0; mm < 4; ++mm) {
      bf16x4 ov;
#pragma unroll
      for (int r = 0; r < 4; ++r) ov[r] = (short)f2bf(acc[mm][nn][r] + bias);
      *(bf16x4*)(xpT + (size_t)nrow * 32768 + m0 + wm + mm * 16 + kq * 4) = ov;
    }
  }
}

// ---------------------------------------------------------------------------
// Persistent recurrent kernel. grid 256 = 4 batch-rows x 64 h-col slices.
// Wave w = gate w (i,f,g,o). W_hh slice in LDS (128KB). h via write-once ring.
__launch_bounds__(256, 1)
__global__ void k_lstm(const unsigned short* __restrict__ whb,
                       const unsigned short* __restrict__ xpT,
                       const float* __restrict__ c0,
                       unsigned short* __restrict__ ring,
                       unsigned int* __restrict__ flags,
                       float* __restrict__ out) {
  const int tid  = threadIdx.x;
  const int lane = tid & 63;
  const int w    = tid >> 6;            // gate index 0..3
  const int jsl  = blockIdx.x & 63;     // h-col slice
  const int brow = blockIdx.x >> 6;     // batch row 0..3
  const int b0   = brow * 16;
  const int j0   = jsl * 16;
  const int col  = lane & 15;
  const int kch  = (lane >> 4) * 8;

  __shared__ bf16x8 WL[4][32][64];      // 128 KB: W_hh fragments
  __shared__ float glds[4][16][17];
  __shared__ unsigned short hs[16][16];

  // stage W_hh fragments into LDS (each thread loads exactly what it reads back)
  {
    const unsigned short* wp = whb + (size_t)(w * 1024 + j0 + col) * 1024 + kch;
#pragma unroll 4
    for (int s = 0; s < 32; ++s) WL[w][s][lane] = *(const bf16x8*)(wp + s * 32);
  }

  const int bl = tid >> 4, cc = tid & 15;
  float c = c0[(b0 + bl) * 1024 + j0 + cc];

  const unsigned short* xprow =
      xpT + (size_t)(w * 1024 + j0 + col) * 32768 + b0 + (lane >> 4) * 4;
  unsigned int* rowflags = flags + (size_t)brow * 512 * 64;

  __syncthreads();  // W staged

  bf16x4 xv = *(const bf16x4*)(xprow);  // step-0 x-proj slice

  for (int t = 0; t < T_STEPS; ++t) {
    // ---- wait for ring slot t (produced at step t-1; slot 0 = h0) ---------
    if (t > 0 && tid < 64) {
      const unsigned int* fp = rowflags + (size_t)(t - 1) * 64 + lane;
      for (;;) {
        unsigned int v = __hip_atomic_load(fp, __ATOMIC_RELAXED,
                                           __HIP_MEMORY_SCOPE_AGENT);
        if (__all(v != 0u)) break;
      }
    }
    __syncthreads();  // #1

    // prefetch next step's x-proj slice (static data, off critical path)
    bf16x4 xv_next = xv;
    if (t < T_STEPS - 1) xv_next = *(const bf16x4*)(xprow + (size_t)(t + 1) * 64);

    // ---- recurrent GEMM: A = ring slot t (normal cached loads) ------------
    const unsigned short* hr =
        ring + (size_t)t * BH + (size_t)(b0 + col) * 1024 + kch;
    f32x4 acc0 = (f32x4){0.f, 0.f, 0.f, 0.f};
    f32x4 acc1 = (f32x4){0.f, 0.f, 0.f, 0.f};
#pragma unroll
    for (int s = 0; s < 32; s += 2) {
      bf16x8 a0 = *(const bf16x8*)(hr + s * 32);
      bf16x8 a1 = *(const bf16x8*)(hr + (s + 1) * 32);
      acc0 = __builtin_amdgcn_mfma_f32_16x16x32_bf16(a0, WL[w][s][lane],     acc0, 0, 0, 0);
      acc1 = __builtin_amdgcn_mfma_f32_16x16x32_bf16(a1, WL[w][s + 1][lane], acc1, 0, 0, 0);
    }

#pragma unroll
    for (int r = 0; r < 4; ++r) {
      float v = (acc0[r] + acc1[r]) + bf2f(xv[r]);
      float g = (w == 2) ? tanh_f(v) : sigm(v);
      glds[w][(lane >> 4) * 4 + r][col] = g;
    }
    xv = xv_next;
    __syncthreads();  // #2

    float ig = glds[0][bl][cc], fg = glds[1][bl][cc];
    float gg = glds[2][bl][cc], og = glds[3][bl][cc];
    c = fg * c + ig * gg;
    float h = og * tanh_f(c);
    hs[bl][cc] = f2bf(h);
    __syncthreads();  // #3

    // ---- publish h into ring slot t+1 (sc1 write-through) + flag ----------
    if (tid < 64) {
      if (t < T_STEPS - 1) {
        const int sb = tid >> 2, sq = tid & 3;
        u64 pv = *(const u64*)&hs[sb][sq * 4];
        u64* dst = (u64*)(ring) + ((size_t)(t + 1) * BH +
                                   (size_t)(b0 + sb) * 1024 + j0 + sq * 4) / 4;
        __hip_atomic_store(dst, pv, __ATOMIC_RELAXED, __HIP_MEMORY_SCOPE_AGENT);
        asm volatile("s_waitcnt vmcnt(0)" ::: "memory");  // drain publish only
        if (tid == 0) {
          __hip_atomic_store(rowflags + (size_t)t * 64 + jsl, 1u,
                             __ATOMIC_RELAXED, __HIP_MEMORY_SCOPE_AGENT);
        }
      }
    }

    // ---- outputs (off the signalling path; drained at next #1) ------------
    const int hoff = (b0 + bl) * 1024 + j0 + cc;
    out[(size_t)t * BH + hoff] = h;
    if (t == T_STEPS - 1) {
      out[(size_t)T_STEPS * BH + hoff] = h;       // hT
      out[(size_t)T_STEPS * BH + BH + hoff] = c;  // cT
    }
  }
}

// ---------------------------------------------------------------------------
extern "C" void kernel_launch(void* const* d_in, const int* in_sizes, int n_in,
                              void* d_out, int out_size, void* d_ws, size_t ws_size,
                              hipStream_t stream) {
  const float* x   = (const float*)d_in[0];
  const float* h0  = (const float*)d_in[1];
  const float* c0  = (const float*)d_in[2];
  const float* Wih = (const float*)d_in[3];
  const float* Whh = (const float*)d_in[4];
  const float* bih = (const float*)d_in[5];
  const float* bhh = (const float*)d_in[6];
  float* out = (float*)d_out;
  char* ws = (char*)d_ws;

  unsigned short* xpT  = (unsigned short*)(ws + OFF_XPT);
  unsigned short* ring = (unsigned short*)(ws + OFF_RING);
  unsigned short* wib  = (unsigned short*)(ws + OFF_WIB);
  unsigned short* whb  = (unsigned short*)(ws + OFF_WHB);
  float*          bsum = (float*)(ws + OFF_BSUM);
  unsigned int*   flg  = (unsigned int*)(ws + OFF_FLG);

  // bf16 x lives in d_out's first 64MB: fully consumed by k_xproj before
  // k_lstm starts writing outputs (kernels are stream-ordered).
  unsigned short* xb = (unsigned short*)d_out;

  hipMemsetAsync(flg, 0, 4 * 512 * 64 * sizeof(unsigned int), stream);

  k_cast_bf16<<<dim3(32768), dim3(256), 0, stream>>>(x, xb, T_STEPS * BATCH * HID);
  k_cast_bf16<<<dim3(4096),  dim3(256), 0, stream>>>(Wih, wib, G4 * HID);
  k_cast_bf16<<<dim3(4096),  dim3(256), 0, stream>>>(Whh, whb, G4 * HID);
  k_cast_bf16<<<dim3(64),    dim3(256), 0, stream>>>(h0, ring, BATCH * HID);  // slot 0
  k_bias<<<dim3(16), dim3(256), 0, stream>>>(bih, bhh, bsum);

  k_xproj<<<dim3(8192), dim3(256), 0, stream>>>(xb, wib, bsum, xpT);
  k_lstm<<<dim3(256), dim3(256), 0, stream>>>(whb, xpT, c0, ring, flg, out);
}